// Round 8
// baseline (412.786 us; speedup 1.0000x reference)
//
#include <hip/hip_runtime.h>
#include <hip/hip_cooperative_groups.h>
#include <cstdint>
#include <cstddef>

namespace cg = cooperative_groups;

#define DEV static __device__ __forceinline__

typedef __attribute__((ext_vector_type(8))) short bf16x8;   // 8 bf16 (4 VGPRs)
typedef __attribute__((ext_vector_type(4))) float f32x4;

constexpr int NB   = 64;     // batch
constexpr int NTOK = 197;    // tokens
constexpr int DIMC = 768;    // channels
constexpr int NH   = 12;     // heads
constexpr int HDIM = 64;     // head dim
constexpr int MTOK = NB * NTOK;   // 12608 rows
constexpr int QKVO = 3 * DIMC;    // 2304
constexpr int BH   = NB * NH;     // 768
constexpr int KROWS = 198;        // staged K rows (jrow clamped to 197)
constexpr int VTS   = 232;        // V^T row stride (464B: bank-walking, not %128B)
constexpr int OBS   = 68;         // O-bounce row stride (136B)
constexpr int GRID_MAX = 512;     // 2 blocks/CU x 256 CUs target

// LDS overlay (ushort units): attn = Ks | Vt | Ob ; gemm = As | Bs
constexpr int LDS_KS = 0;
constexpr int LDS_VT = KROWS * 64;                 // 12672
constexpr int LDS_OB = LDS_VT + HDIM * VTS;        // 27520
constexpr int LDS_TOT = LDS_OB + 4 * 16 * OBS;     // 31872 u16 = 63744 B

DEV unsigned short f2bf(float f) {
  union { float f; uint32_t u; } v; v.f = f;
  uint32_t u = v.u;
  return (unsigned short)((u + 0x7FFFu + ((u >> 16) & 1u)) >> 16);  // RNE, finite
}

DEV uint32_t pack_bf2(float a, float b) {
  return (uint32_t)f2bf(a) | ((uint32_t)f2bf(b) << 16);
}

DEV f32x4 mfma16(bf16x8 a, bf16x8 b, f32x4 c) {
  return __builtin_amdgcn_mfma_f32_16x16x32_bf16(a, b, c, 0, 0, 0);
}

DEV void async_cp16(const unsigned short* g, unsigned short* l) {
  __builtin_amdgcn_global_load_lds(
      (__attribute__((address_space(1))) void*)g,
      (__attribute__((address_space(3))) void*)l, 16, 0, 0);
}

// supertile swizzle: groups of 8 M-tiles, N-major inside the group.
DEV void swizzle_mn(int lin, int gridM, int gridN, int& mbase, int& nbase) {
  int per = 8 * gridN;
  int sup = lin / per;
  int bm  = sup * 8;
  int Gm  = gridM - bm; if (Gm > 8) Gm = 8;
  int rem = lin - sup * per;
  int n   = rem / Gm;
  int mm  = rem - n * Gm;
  mbase = (bm + mm) * 128;
  nbase = n * 128;
}

// ---------------- NT-GEMM main loop (m97 structure), LDS passed in ----------------
DEV void gemm_mainloop(const unsigned short* __restrict__ A, int Arows,
                       const unsigned short* __restrict__ Bw,
                       unsigned short* As, unsigned short* Bs,
                       int mbase, int nbase, f32x4 acc[4][4]) {
  const int tid  = threadIdx.x;
  const int lane = tid & 63;
  const int wave = tid >> 6;
  const int wm = wave & 1, wn = wave >> 1;
  const int l16 = lane & 15, quad = lane >> 4;

  for (int k0 = 0; k0 < DIMC; k0 += 64) {
#pragma unroll
    for (int i = 0; i < 4; ++i) {
      int c = i * 256 + tid;
      int row = c >> 3, cc = c & 7;
      int gc = (cc ^ (row & 7)) * 8;
      int ar = mbase + row; ar = ar < Arows ? ar : Arows - 1;
      async_cp16(A  + (size_t)ar * DIMC + k0 + gc, As + c * 8);
      async_cp16(Bw + (size_t)(nbase + row) * DIMC + k0 + gc, Bs + c * 8);
    }
    __syncthreads();
#pragma unroll
    for (int kk = 0; kk < 64; kk += 32) {
      const int cw = (kk >> 3) + quad;
      bf16x8 af[4], bfr[4];
#pragma unroll
      for (int mi = 0; mi < 4; ++mi) {
        int r = wm * 64 + mi * 16 + l16;
        af[mi] = *(const bf16x8*)(As + r * 64 + (cw ^ (r & 7)) * 8);
      }
#pragma unroll
      for (int ni = 0; ni < 4; ++ni) {
        int r = wn * 64 + ni * 16 + l16;
        bfr[ni] = *(const bf16x8*)(Bs + r * 64 + (cw ^ (r & 7)) * 8);
      }
#pragma unroll
      for (int mi = 0; mi < 4; ++mi)
#pragma unroll
        for (int ni = 0; ni < 4; ++ni)
          acc[mi][ni] = mfma16(af[mi], bfr[ni], acc[mi][ni]);
    }
    __syncthreads();
  }
}

// ---------------- QKV GEMM tile body (epilogue scatters to [3][b][h][n][hd]) ----------------
DEV void qkv_tile(const unsigned short* __restrict__ xb,
                  const unsigned short* __restrict__ wqb,
                  unsigned short* __restrict__ qkvb,
                  int tile, unsigned short* As, unsigned short* Bs) {
  const int tid = threadIdx.x, lane = tid & 63, wave = tid >> 6;
  const int wm = wave & 1, wn = wave >> 1;
  const int l16 = lane & 15, quad = lane >> 4;
  const int gridM = (MTOK + 127) / 128, gridN = QKVO / 128;
  int mbase, nbase;
  swizzle_mn(tile, gridM, gridN, mbase, nbase);

  f32x4 acc[4][4];
#pragma unroll
  for (int i = 0; i < 4; ++i)
#pragma unroll
    for (int j = 0; j < 4; ++j) acc[i][j] = {0.f, 0.f, 0.f, 0.f};
  gemm_mainloop(xb, MTOK, wqb, As, Bs, mbase, nbase, acc);

  const int oc64  = nbase + wn * 64;
  const int which = oc64 / DIMC;
  const int h     = (oc64 % DIMC) / HDIM;
#pragma unroll
  for (int mi = 0; mi < 4; ++mi) {
    int t0 = mbase + wm * 64 + mi * 16 + quad * 4;
#pragma unroll
    for (int r = 0; r < 4; ++r) {
      int tt = t0 + r;
      if (tt < MTOK) {
        int b = tt / NTOK, n = tt - b * NTOK;
        size_t base = ((size_t)((which * NB + b) * NH + h) * NTOK + n) * HDIM;
#pragma unroll
        for (int ni = 0; ni < 4; ++ni)
          qkvb[base + ni * 16 + l16] = f2bf(acc[mi][ni][r]);
      }
    }
  }
}

// ---------------- proj GEMM tile body (+bias+residual, fp32 out) ----------------
DEV void proj_tile(const unsigned short* __restrict__ attb,
                   const unsigned short* __restrict__ wpb,
                   const float* __restrict__ bias,
                   const float* __restrict__ xres,
                   float* __restrict__ out,
                   int tile, unsigned short* As, unsigned short* Bs) {
  const int tid = threadIdx.x, lane = tid & 63, wave = tid >> 6;
  const int wm = wave & 1, wn = wave >> 1;
  const int l16 = lane & 15, quad = lane >> 4;
  const int gridM = (MTOK + 127) / 128, gridN = DIMC / 128;
  int mbase, nbase;
  swizzle_mn(tile, gridM, gridN, mbase, nbase);

  f32x4 acc[4][4];
#pragma unroll
  for (int i = 0; i < 4; ++i)
#pragma unroll
    for (int j = 0; j < 4; ++j) acc[i][j] = {0.f, 0.f, 0.f, 0.f};
  gemm_mainloop(attb, MTOK, wpb, As, Bs, mbase, nbase, acc);

  const int oc = nbase + wn * 64;
#pragma unroll
  for (int mi = 0; mi < 4; ++mi) {
    int t0 = mbase + wm * 64 + mi * 16 + quad * 4;
#pragma unroll
    for (int r = 0; r < 4; ++r) {
      int tt = t0 + r;
      if (tt < MTOK) {
        size_t rowb = (size_t)tt * DIMC;
#pragma unroll
        for (int ni = 0; ni < 4; ++ni) {
          int o = oc + ni * 16 + l16;
          out[rowb + o] = acc[mi][ni][r] + bias[o] + xres[rowb + o];
        }
      }
    }
  }
}

// ---------------- attention for one head, Q-tile range [mtLo,mtHi) ----------------
DEV void attn_head(const unsigned short* __restrict__ qkv,
                   const float* __restrict__ scale,
                   unsigned short* __restrict__ aout,
                   int bh, int mtLo, int mtHi, unsigned short* lds) {
  unsigned short* Ks = lds + LDS_KS;
  unsigned short* Vt = lds + LDS_VT;
  unsigned short* Ob = lds + LDS_OB;

  const int tid = threadIdx.x, lane = tid & 63, wave = tid >> 6;
  const int l16 = lane & 15, quad = lane >> 4;
  const int b = bh / NH, h = bh - b * NH;

  const unsigned short* qg = qkv + (size_t)bh * (NTOK * HDIM);
  const unsigned short* kg = qkv + (size_t)(BH + bh) * (NTOK * HDIM);
  const unsigned short* vg = qkv + (size_t)(2 * BH + bh) * (NTOK * HDIM);
  const float sc = scale[h];

  // stage K via DMA: rows 0..197 (1584 x 16B chunks)
#pragma unroll
  for (int i = 0; i < 7; ++i) {
    int c = i * 256 + tid;
    if (c < KROWS * 8) {
      int row = c >> 3, cc = c & 7;
      async_cp16(kg + (size_t)row * 64 + ((cc ^ (row & 7)) * 8), Ks + c * 8);
    }
  }
  // build V^T: coalesced 128B row reads + bank-walking b128 writes
  {
    const int dcol = tid & 63;
    const int slab = tid >> 6;
#pragma unroll
    for (int p = 0; p < 7; ++p) {
      int n0 = p * 32 + slab * 8;
      union { unsigned short us[8]; bf16x8 v; } tr;
#pragma unroll
      for (int i = 0; i < 8; ++i) {
        int n = n0 + i; n = n > NTOK - 1 ? NTOK - 1 : n;
        tr.us[i] = vg[(size_t)n * HDIM + dcol];
      }
      *(bf16x8*)(Vt + dcol * VTS + n0) = tr.v;
    }
  }
  __syncthreads();   // drains DMA vmcnt + Vt lgkm

  const int srcA  = l16 + ((quad & 1) << 5);
  const int srcB  = srcA + 16;
  const int stsel = quad >> 1;
  unsigned short* ob = Ob + wave * (16 * OBS);

  for (int mt = mtLo + wave; mt < mtHi; mt += 4) {
    int qr = mt * 16 + l16; if (qr > NTOK - 1) qr = NTOK - 1;
    bf16x8 qb0 = *(const bf16x8*)(qg + (size_t)qr * 64 + quad * 8);
    bf16x8 qb1 = *(const bf16x8*)(qg + (size_t)qr * 64 + 32 + quad * 8);
    const int mg = mt * 16 + l16;

    // batched S^T = K.Q^T (26 MFMAs; jc=6,st=1 keys all masked)
    f32x4 s[7][2];
#pragma unroll
    for (int jc = 0; jc < 7; ++jc)
#pragma unroll
      for (int st = 0; st < 2; ++st) {
        if (jc == 6 && st == 1) { s[6][1] = {0.f, 0.f, 0.f, 0.f}; continue; }
        int jrow = (jc * 2 + st) * 16 + l16;
        jrow = jrow > NTOK ? NTOK : jrow;        // clamp (masked rows)
        const unsigned short* kr = Ks + jrow * 64;
        bf16x8 ka0 = *(const bf16x8*)(kr + (quad       ^ (jrow & 7)) * 8);
        bf16x8 ka1 = *(const bf16x8*)(kr + ((4 + quad) ^ (jrow & 7)) * 8);
        f32x4 t = {0.f, 0.f, 0.f, 0.f};
        t = mfma16(ka0, qb0, t);
        t = mfma16(ka1, qb1, t);
        s[jc][st] = t;
      }

    // softmax over keys (row = l16)
    float cmax = -1e30f;
#pragma unroll
    for (int jc = 0; jc < 7; ++jc)
#pragma unroll
      for (int st = 0; st < 2; ++st)
#pragma unroll
        for (int r = 0; r < 4; ++r) {
          int jg = jc * 32 + st * 16 + quad * 4 + r;
          float v = s[jc][st][r] * sc;
          v = (jg >= NTOK || jg == mg) ? -1e30f : v;
          s[jc][st][r] = v;
          cmax = fmaxf(cmax, v);
        }
    cmax = fmaxf(cmax, __shfl_xor(cmax, 16));
    cmax = fmaxf(cmax, __shfl_xor(cmax, 32));
    float psum = 0.f;
#pragma unroll
    for (int jc = 0; jc < 7; ++jc)
#pragma unroll
      for (int st = 0; st < 2; ++st)
#pragma unroll
        for (int r = 0; r < 4; ++r) {
          float e = __expf(s[jc][st][r] - cmax);
          psum += e;
          s[jc][st][r] = e;
        }
    psum += __shfl_xor(psum, 16);
    psum += __shfl_xor(psum, 32);
    const float inv = 1.0f / psum;

    // PV: O^T = V^T.P^T; P^T B-frags via shfl, V^T b128 from LDS
    f32x4 oacc[4];
#pragma unroll
    for (int dt = 0; dt < 4; ++dt) oacc[dt] = {0.f, 0.f, 0.f, 0.f};

#pragma unroll
    for (int jc = 0; jc < 7; ++jc) {
      uint32_t u0 = pack_bf2(s[jc][0][0], s[jc][0][1]);
      uint32_t v0 = pack_bf2(s[jc][0][2], s[jc][0][3]);
      uint32_t u1 = pack_bf2(s[jc][1][0], s[jc][1][1]);
      uint32_t v1 = pack_bf2(s[jc][1][2], s[jc][1][3]);
      uint32_t au0 = (uint32_t)__shfl((int)u0, srcA);
      uint32_t av0 = (uint32_t)__shfl((int)v0, srcA);
      uint32_t au1 = (uint32_t)__shfl((int)u1, srcA);
      uint32_t av1 = (uint32_t)__shfl((int)v1, srcA);
      uint32_t bu0 = (uint32_t)__shfl((int)u0, srcB);
      uint32_t bv0 = (uint32_t)__shfl((int)v0, srcB);
      uint32_t bu1 = (uint32_t)__shfl((int)u1, srcB);
      uint32_t bv1 = (uint32_t)__shfl((int)v1, srcB);
      union { uint32_t u[4]; bf16x8 v; } pb;
      pb.u[0] = stsel ? au1 : au0;
      pb.u[1] = stsel ? av1 : av0;
      pb.u[2] = stsel ? bu1 : bu0;
      pb.u[3] = stsel ? bv1 : bv0;
#pragma unroll
      for (int dt = 0; dt < 4; ++dt) {
        bf16x8 va = *(const bf16x8*)(Vt + (dt * 16 + l16) * VTS +
                                     jc * 32 + quad * 8);
        oacc[dt] = mfma16(va, pb.v, oacc[dt]);
      }
    }

    // O store via per-wave LDS bounce -> full 128B line stores
#pragma unroll
    for (int dt = 0; dt < 4; ++dt) {
      ushort4 pk;
      pk.x = f2bf(oacc[dt][0] * inv);
      pk.y = f2bf(oacc[dt][1] * inv);
      pk.z = f2bf(oacc[dt][2] * inv);
      pk.w = f2bf(oacc[dt][3] * inv);
      *(ushort4*)(ob + l16 * OBS + dt * 16 + quad * 4) = pk;
    }
    __asm__ __volatile__("s_waitcnt lgkmcnt(0)" ::: "memory");
#pragma unroll
    for (int rnd = 0; rnd < 4; ++rnd) {
      int q   = rnd * 4 + (lane >> 4);
      int o8  = lane & 15;
      uint2 d8 = *(const uint2*)(ob + q * OBS + o8 * 4);
      int qrow = mt * 16 + q;
      if (qrow < NTOK) {
        size_t obase = (size_t)(b * NTOK + qrow) * DIMC + h * HDIM;
        *(uint2*)(aout + obase + o8 * 4) = d8;
      }
    }
  }
}

// ---------------- cvt segments ----------------
constexpr int CVT_B1 = (MTOK * DIMC) / 1024;   // 9456
constexpr int CVT_B2 = (QKVO * DIMC) / 1024;   // 1728
constexpr int CVT_B3 = (DIMC * DIMC) / 1024;   //  576
constexpr int CVT_NB = CVT_B1 + CVT_B2 + CVT_B3;

DEV void cvt_block(const float* __restrict__ x, const float* __restrict__ wq,
                   const float* __restrict__ wp, unsigned short* __restrict__ xb,
                   unsigned short* __restrict__ wqb, unsigned short* __restrict__ wpb,
                   int blk) {
  const float* s; unsigned short* d; int bb = blk;
  if (bb < CVT_B1)                { s = x;  d = xb; }
  else if (bb < CVT_B1 + CVT_B2)  { s = wq; d = wqb; bb -= CVT_B1; }
  else                            { s = wp; d = wpb; bb -= CVT_B1 + CVT_B2; }
  int i = (bb * 256 + (int)threadIdx.x) * 4;
  float4 f = *(const float4*)(s + i);
  ushort4 o;
  o.x = f2bf(f.x); o.y = f2bf(f.y); o.z = f2bf(f.z); o.w = f2bf(f.w);
  *(ushort4*)(d + i) = o;
}

// ================= standalone kernels (fallback path, = R6) =================
__global__ void __launch_bounds__(256) cvt_all(const float* __restrict__ x,
                                               const float* __restrict__ wq,
                                               const float* __restrict__ wp,
                                               unsigned short* __restrict__ xb,
                                               unsigned short* __restrict__ wqb,
                                               unsigned short* __restrict__ wpb) {
  cvt_block(x, wq, wp, xb, wqb, wpb, blockIdx.x);
}

__global__ void __launch_bounds__(256) gemm_qkv(const unsigned short* __restrict__ A,
                                                const unsigned short* __restrict__ Bw,
                                                unsigned short* __restrict__ qkv) {
  __shared__ __align__(16) unsigned short lds[16384];
  qkv_tile(A, Bw, qkv, blockIdx.x, lds, lds + 8192);
}

__global__ void __launch_bounds__(256) gemm_proj(const unsigned short* __restrict__ A,
                                                 const unsigned short* __restrict__ Bw,
                                                 const float* __restrict__ bias,
                                                 const float* __restrict__ xres,
                                                 float* __restrict__ out) {
  __shared__ __align__(16) unsigned short lds[16384];
  proj_tile(A, Bw, bias, xres, out, blockIdx.x, lds, lds + 8192);
}

__global__ void __launch_bounds__(256, 2) attn_fused(const unsigned short* __restrict__ qkv,
                                                     const float* __restrict__ scale,
                                                     unsigned short* __restrict__ aout) {
  __shared__ __align__(16) unsigned short lds[LDS_TOT];
  attn_head(qkv, scale, aout, blockIdx.x, 0, 13, lds);
}

// ================= ONE cooperative persistent kernel =================
__global__ void __launch_bounds__(256, 2)
mega(const float* __restrict__ x, const float* __restrict__ scale,
     const float* __restrict__ wqkv, const float* __restrict__ wproj,
     const float* __restrict__ bproj, float* __restrict__ out,
     unsigned short* __restrict__ xb, unsigned short* __restrict__ wqb,
     unsigned short* __restrict__ wpb, unsigned short* __restrict__ qkvb) {
  __shared__ __align__(16) unsigned short lds[LDS_TOT];   // 63744 B
  cg::grid_group grid = cg::this_grid();
  const int nblk = (int)gridDim.x;
  unsigned short* attb = xb;           // attn out aliases xb (dead after qkv)

  // phase 1: f32 -> bf16 converts
  for (int blk = blockIdx.x; blk < CVT_NB; blk += nblk)
    cvt_block(x, wqkv, wproj, xb, wqb, wpb, blk);
  grid.sync();

  // phase 2: QKV GEMM (1782 tiles, persistent)
  {
    const int nt = ((MTOK + 127) / 128) * (QKVO / 128);
    for (int t = blockIdx.x; t < nt; t += nblk) {
      qkv_tile(xb, wqb, qkvb, t, lds, lds + 8192);
      __syncthreads();
    }
  }
  grid.sync();

  // phase 3: attention (1536 half-head items)
  for (int w = blockIdx.x; w < 2 * BH; w += nblk) {
    int bh   = w < BH ? w : w - BH;
    int lo   = w < BH ? 0 : 7;
    int hi   = w < BH ? 7 : 13;
    attn_head(qkvb, scale, attb, bh, lo, hi, lds);
    __syncthreads();   // LDS reuse across items
  }
  grid.sync();

  // phase 4: proj GEMM + bias + residual (594 tiles)
  {
    const int nt = ((MTOK + 127) / 128) * (DIMC / 128);
    for (int t = blockIdx.x; t < nt; t += nblk) {
      proj_tile(attb, wpb, bproj, x, out, t, lds, lds + 8192);
      __syncthreads();
    }
  }
}

// ---------------- launcher ----------------
extern "C" void kernel_launch(void* const* d_in, const int* in_sizes, int n_in,
                              void* d_out, int out_size, void* d_ws, size_t ws_size,
                              hipStream_t stream) {
  const float* x     = (const float*)d_in[0];
  const float* scale = (const float*)d_in[1];
  const float* wqkv  = (const float*)d_in[2];
  const float* wproj = (const float*)d_in[3];
  const float* bproj = (const float*)d_in[4];
  float* out = (float*)d_out;

  unsigned short* xb   = (unsigned short*)d_ws;
  unsigned short* wqb  = xb  + (size_t)MTOK * DIMC;
  unsigned short* wpb  = wqb + (size_t)QKVO * DIMC;
  unsigned short* qkvb = wpb + (size_t)DIMC * DIMC;

  // ---- capture-safe queries to size a viable cooperative grid ----
  int dev = 0; (void)hipGetDevice(&dev);
  int coop = 0;
  (void)hipDeviceGetAttribute(&coop, hipDeviceAttributeCooperativeLaunch, dev);
  int ncu = 0;
  (void)hipDeviceGetAttribute(&ncu, hipDeviceAttributeMultiprocessorCount, dev);
  int maxb = 0;
  hipError_t qe = hipOccupancyMaxActiveBlocksPerMultiprocessor(
      &maxb, (const void*)mega, 256, 0);

  hipError_t e = hipErrorUnknown;
  if (coop && qe == hipSuccess && maxb >= 1 && ncu > 0) {
    int grid = maxb * ncu;
    if (grid > GRID_MAX) grid = GRID_MAX;
    void* args[] = {(void*)&x, (void*)&scale, (void*)&wqkv, (void*)&wproj,
                    (void*)&bproj, (void*)&out, (void*)&xb, (void*)&wqb,
                    (void*)&wpb, (void*)&qkvb};
    e = hipLaunchCooperativeKernel((const void*)mega, dim3(grid), dim3(256),
                                   args, 0, stream);
  }
  if (e != hipSuccess) {
    // fallback: the proven R6 4-kernel path (identical math)
    const int gmM = (MTOK + 127) / 128;      // 99
    cvt_all<<<CVT_NB, 256, 0, stream>>>(x, wqkv, wproj, xb, wqb, wpb);
    gemm_qkv<<<gmM * (QKVO / 128), 256, 0, stream>>>(xb, wqb, qkvb);
    attn_fused<<<BH, 256, 0, stream>>>(qkvb, scale, xb);
    gemm_proj<<<gmM * (DIMC / 128), 256, 0, stream>>>(xb, wpb, bproj, x, out);
  }
}

// Round 9
// 239.478 us; speedup vs baseline: 1.7237x; 1.7237x over previous
//
#include <hip/hip_runtime.h>
#include <cstdint>
#include <cstddef>

#define DEV static __device__ __forceinline__

typedef __attribute__((ext_vector_type(8))) short bf16x8;   // 8 bf16 (4 VGPRs)
typedef __attribute__((ext_vector_type(4))) float f32x4;

constexpr int NB   = 64;     // batch
constexpr int NTOK = 197;    // tokens
constexpr int DIMC = 768;    // channels
constexpr int NH   = 12;     // heads
constexpr int HDIM = 64;     // head dim
constexpr int MTOK = NB * NTOK;   // 12608 rows
constexpr int QKVO = 3 * DIMC;    // 2304
constexpr int BH   = NB * NH;     // 768
constexpr int KROWS = 198;        // staged K rows (jrow clamped to 197)
constexpr int VTS   = 232;        // V^T row stride (464B, 16B-aligned)
constexpr int OBS   = 68;         // O-bounce row stride (136B)
constexpr int GM    = (MTOK + 127) / 128;   // 99 M-tiles

DEV unsigned short f2bf(float f) {
  union { float f; uint32_t u; } v; v.f = f;
  uint32_t u = v.u;
  return (unsigned short)((u + 0x7FFFu + ((u >> 16) & 1u)) >> 16);  // RNE, finite
}

DEV uint32_t pack_bf2(float a, float b) {
  return (uint32_t)f2bf(a) | ((uint32_t)f2bf(b) << 16);
}

DEV f32x4 mfma16(bf16x8 a, bf16x8 b, f32x4 c) {
  return __builtin_amdgcn_mfma_f32_16x16x32_bf16(a, b, c, 0, 0, 0);
}

DEV void async_cp16(const unsigned short* g, unsigned short* l) {
  __builtin_amdgcn_global_load_lds(
      (__attribute__((address_space(1))) void*)g,
      (__attribute__((address_space(3))) void*)l, 16, 0, 0);
}

// supertile swizzle: groups of 8 M-tiles, N-major inside the group.
DEV void swizzle_mn(int lin, int gridM, int gridN, int& mbase, int& nbase) {
  int per = 8 * gridN;
  int sup = lin / per;
  int bm  = sup * 8;
  int Gm  = gridM - bm; if (Gm > 8) Gm = 8;
  int rem = lin - sup * per;
  int n   = rem / Gm;
  int mm  = rem - n * Gm;
  mbase = (bm + mm) * 128;
  nbase = n * 128;
}

// ---------------- f32 -> bf16 converts: one kernel, 4 float4/thread ----------------
constexpr int CVB1 = (MTOK * DIMC) / 4096;   // 2364
constexpr int CVB2 = (QKVO * DIMC) / 4096;   //  432
constexpr int CVB3 = (DIMC * DIMC) / 4096;   //  144
constexpr int CVNB = CVB1 + CVB2 + CVB3;     // 2940

__global__ void __launch_bounds__(256) cvt_all(const float* __restrict__ x,
                                               const float* __restrict__ wq,
                                               const float* __restrict__ wp,
                                               unsigned short* __restrict__ xb,
                                               unsigned short* __restrict__ wqb,
                                               unsigned short* __restrict__ wpb) {
  int blk = blockIdx.x;
  const float* s; unsigned short* d;
  if (blk < CVB1)               { s = x;  d = xb; }
  else if (blk < CVB1 + CVB2)   { s = wq; d = wqb; blk -= CVB1; }
  else                          { s = wp; d = wpb; blk -= CVB1 + CVB2; }
  size_t base = (size_t)blk * 4096 + (size_t)threadIdx.x * 4;
#pragma unroll
  for (int j = 0; j < 4; ++j) {
    size_t i = base + (size_t)j * 1024;
    float4 f = *(const float4*)(s + i);
    ushort4 o;
    o.x = f2bf(f.x); o.y = f2bf(f.y); o.z = f2bf(f.z); o.w = f2bf(f.w);
    *(ushort4*)(d + i) = o;
  }
}

// ---------------- NT-GEMM main loop (m97 structure) ----------------
DEV void gemm_mainloop(const unsigned short* __restrict__ A, int Arows,
                       const unsigned short* __restrict__ Bw,
                       unsigned short* As, unsigned short* Bs,
                       int mbase, int nbase, f32x4 acc[4][4]) {
  const int tid  = threadIdx.x;
  const int lane = tid & 63;
  const int wave = tid >> 6;
  const int wm = wave & 1, wn = wave >> 1;
  const int l16 = lane & 15, quad = lane >> 4;

  for (int k0 = 0; k0 < DIMC; k0 += 64) {
#pragma unroll
    for (int i = 0; i < 4; ++i) {
      int c = i * 256 + tid;
      int row = c >> 3, cc = c & 7;
      int gc = (cc ^ (row & 7)) * 8;
      int ar = mbase + row; ar = ar < Arows ? ar : Arows - 1;
      async_cp16(A  + (size_t)ar * DIMC + k0 + gc, As + c * 8);
      async_cp16(Bw + (size_t)(nbase + row) * DIMC + k0 + gc, Bs + c * 8);
    }
    __syncthreads();
#pragma unroll
    for (int kk = 0; kk < 64; kk += 32) {
      const int cw = (kk >> 3) + quad;
      bf16x8 af[4], bfr[4];
#pragma unroll
      for (int mi = 0; mi < 4; ++mi) {
        int r = wm * 64 + mi * 16 + l16;
        af[mi] = *(const bf16x8*)(As + r * 64 + (cw ^ (r & 7)) * 8);
      }
#pragma unroll
      for (int ni = 0; ni < 4; ++ni) {
        int r = wn * 64 + ni * 16 + l16;
        bfr[ni] = *(const bf16x8*)(Bs + r * 64 + (cw ^ (r & 7)) * 8);
      }
#pragma unroll
      for (int mi = 0; mi < 4; ++mi)
#pragma unroll
        for (int ni = 0; ni < 4; ++ni)
          acc[mi][ni] = mfma16(af[mi], bfr[ni], acc[mi][ni]);
    }
    __syncthreads();
  }
}

// ---------------- QKV GEMM part: N-tile range [nOff, nOff+gridN) ----------------
// Split into a QK dispatch (12 N-tiles) and a V dispatch (6 N-tiles) so no
// single ~63us kernel monopolizes the rocprof top-5 (diagnostic visibility).
__global__ void __launch_bounds__(256) gemm_qkv_part(const unsigned short* __restrict__ A,
                                                     const unsigned short* __restrict__ Bw,
                                                     unsigned short* __restrict__ qkv,
                                                     int nOff, int gridN) {
  __shared__ __align__(16) unsigned short lds[16384];
  unsigned short* As = lds;
  unsigned short* Bs = lds + 8192;
  const int tid = threadIdx.x, lane = tid & 63, wave = tid >> 6;
  const int wm = wave & 1, wn = wave >> 1;
  const int l16 = lane & 15, quad = lane >> 4;
  int mbase, nbase;
  swizzle_mn(blockIdx.x, GM, gridN, mbase, nbase);
  nbase += nOff * 128;                 // absolute output-channel base

  f32x4 acc[4][4];
#pragma unroll
  for (int i = 0; i < 4; ++i)
#pragma unroll
    for (int j = 0; j < 4; ++j) acc[i][j] = {0.f, 0.f, 0.f, 0.f};
  gemm_mainloop(A, MTOK, Bw, As, Bs, mbase, nbase, acc);

  const int oc64  = nbase + wn * 64;   // 64-aligned -> uniform which/h
  const int which = oc64 / DIMC;
  const int h     = (oc64 % DIMC) / HDIM;
#pragma unroll
  for (int mi = 0; mi < 4; ++mi) {
    int t0 = mbase + wm * 64 + mi * 16 + quad * 4;
#pragma unroll
    for (int r = 0; r < 4; ++r) {
      int t = t0 + r;
      if (t < MTOK) {
        int b = t / NTOK, n = t - b * NTOK;
        size_t base = ((size_t)((which * NB + b) * NH + h) * NTOK + n) * HDIM;
#pragma unroll
        for (int ni = 0; ni < 4; ++ni)
          qkv[base + ni * 16 + l16] = f2bf(acc[mi][ni][r]);
      }
    }
  }
}

// ---------------- Proj GEMM + bias + residual (fp32 out) ----------------
__global__ void __launch_bounds__(256) gemm_proj(const unsigned short* __restrict__ A,
                                                 const unsigned short* __restrict__ Bw,
                                                 const float* __restrict__ bias,
                                                 const float* __restrict__ xres,
                                                 float* __restrict__ out) {
  __shared__ __align__(16) unsigned short lds[16384];
  unsigned short* As = lds;
  unsigned short* Bs = lds + 8192;
  const int tid = threadIdx.x, lane = tid & 63, wave = tid >> 6;
  const int wm = wave & 1, wn = wave >> 1;
  const int l16 = lane & 15, quad = lane >> 4;
  int mbase, nbase;
  swizzle_mn(blockIdx.x, GM, DIMC / 128, mbase, nbase);

  f32x4 acc[4][4];
#pragma unroll
  for (int i = 0; i < 4; ++i)
#pragma unroll
    for (int j = 0; j < 4; ++j) acc[i][j] = {0.f, 0.f, 0.f, 0.f};
  gemm_mainloop(A, MTOK, Bw, As, Bs, mbase, nbase, acc);

  const int oc = nbase + wn * 64;
#pragma unroll
  for (int mi = 0; mi < 4; ++mi) {
    int t0 = mbase + wm * 64 + mi * 16 + quad * 4;
#pragma unroll
    for (int r = 0; r < 4; ++r) {
      int t = t0 + r;
      if (t < MTOK) {
        size_t rowb = (size_t)t * DIMC;
#pragma unroll
        for (int ni = 0; ni < 4; ++ni) {
          int o = oc + ni * 16 + l16;
          out[rowb + o] = acc[mi][ni][r] + bias[o] + xres[rowb + o];
        }
      }
    }
  }
}

// ---------------- fused attention: 768 blocks x 1 head (R6-proven) ----------------
__global__ void __launch_bounds__(256, 2) attn_fused(const unsigned short* __restrict__ qkv,
                                                     const float* __restrict__ scale,
                                                     unsigned short* __restrict__ aout) {
  __shared__ __align__(16) unsigned short Ks[KROWS * 64];        // 25344 B
  __shared__ __align__(16) unsigned short Vt[HDIM * VTS];        // 29696 B
  __shared__ __align__(16) unsigned short Ob[4 * 16 * OBS];      //  8704 B

  const int tid = threadIdx.x, lane = tid & 63, wave = tid >> 6;
  const int l16 = lane & 15, quad = lane >> 4;
  const int bh = blockIdx.x;
  const int b = bh / NH, h = bh - b * NH;

  const unsigned short* qg = qkv + (size_t)bh * (NTOK * HDIM);
  const unsigned short* kg = qkv + (size_t)(BH + bh) * (NTOK * HDIM);
  const unsigned short* vg = qkv + (size_t)(2 * BH + bh) * (NTOK * HDIM);
  const float sc = scale[h];

  // stage K via DMA: rows 0..197
#pragma unroll
  for (int i = 0; i < 7; ++i) {
    int c = i * 256 + tid;
    if (c < KROWS * 8) {
      int row = c >> 3, cc = c & 7;
      async_cp16(kg + (size_t)row * 64 + ((cc ^ (row & 7)) * 8), Ks + c * 8);
    }
  }
  // build V^T: coalesced 128B row reads + b128 writes at stride VTS
  {
    const int dcol = tid & 63;
    const int slab = tid >> 6;
#pragma unroll
    for (int p = 0; p < 7; ++p) {
      int n0 = p * 32 + slab * 8;
      union { unsigned short us[8]; bf16x8 v; } tr;
#pragma unroll
      for (int i = 0; i < 8; ++i) {
        int n = n0 + i; n = n > NTOK - 1 ? NTOK - 1 : n;
        tr.us[i] = vg[(size_t)n * HDIM + dcol];
      }
      *(bf16x8*)(Vt + dcol * VTS + n0) = tr.v;
    }
  }
  __syncthreads();

  const int srcA  = l16 + ((quad & 1) << 5);
  const int srcB  = srcA + 16;
  const int stsel = quad >> 1;
  unsigned short* ob = Ob + wave * (16 * OBS);

  for (int mt = wave; mt < 13; mt += 4) {
    int qr = mt * 16 + l16; if (qr > NTOK - 1) qr = NTOK - 1;
    bf16x8 qb0 = *(const bf16x8*)(qg + (size_t)qr * 64 + quad * 8);
    bf16x8 qb1 = *(const bf16x8*)(qg + (size_t)qr * 64 + 32 + quad * 8);
    const int mg = mt * 16 + l16;

    // batched S^T = K.Q^T (26 MFMAs; jc=6,st=1 keys all masked)
    f32x4 s[7][2];
#pragma unroll
    for (int jc = 0; jc < 7; ++jc)
#pragma unroll
      for (int st = 0; st < 2; ++st) {
        if (jc == 6 && st == 1) { s[6][1] = {0.f, 0.f, 0.f, 0.f}; continue; }
        int jrow = (jc * 2 + st) * 16 + l16;
        jrow = jrow > NTOK ? NTOK : jrow;
        const unsigned short* kr = Ks + jrow * 64;
        bf16x8 ka0 = *(const bf16x8*)(kr + (quad       ^ (jrow & 7)) * 8);
        bf16x8 ka1 = *(const bf16x8*)(kr + ((4 + quad) ^ (jrow & 7)) * 8);
        f32x4 t = {0.f, 0.f, 0.f, 0.f};
        t = mfma16(ka0, qb0, t);
        t = mfma16(ka1, qb1, t);
        s[jc][st] = t;
      }

    // softmax over keys (row = l16)
    float cmax = -1e30f;
#pragma unroll
    for (int jc = 0; jc < 7; ++jc)
#pragma unroll
      for (int st = 0; st < 2; ++st)
#pragma unroll
        for (int r = 0; r < 4; ++r) {
          int jg = jc * 32 + st * 16 + quad * 4 + r;
          float v = s[jc][st][r] * sc;
          v = (jg >= NTOK || jg == mg) ? -1e30f : v;
          s[jc][st][r] = v;
          cmax = fmaxf(cmax, v);
        }
    cmax = fmaxf(cmax, __shfl_xor(cmax, 16));
    cmax = fmaxf(cmax, __shfl_xor(cmax, 32));
    float psum = 0.f;
#pragma unroll
    for (int jc = 0; jc < 7; ++jc)
#pragma unroll
      for (int st = 0; st < 2; ++st)
#pragma unroll
        for (int r = 0; r < 4; ++r) {
          float e = __expf(s[jc][st][r] - cmax);
          psum += e;
          s[jc][st][r] = e;
        }
    psum += __shfl_xor(psum, 16);
    psum += __shfl_xor(psum, 32);
    const float inv = 1.0f / psum;

    // PV: O^T = V^T.P^T; P^T B-frags via shfl, V^T b128 from LDS
    f32x4 oacc[4];
#pragma unroll
    for (int dt = 0; dt < 4; ++dt) oacc[dt] = {0.f, 0.f, 0.f, 0.f};

#pragma unroll
    for (int jc = 0; jc < 7; ++jc) {
      uint32_t u0 = pack_bf2(s[jc][0][0], s[jc][0][1]);
      uint32_t v0 = pack_bf2(s[jc][0][2], s[jc][0][3]);
      uint32_t u1 = pack_bf2(s[jc][1][0], s[jc][1][1]);
      uint32_t v1 = pack_bf2(s[jc][1][2], s[jc][1][3]);
      uint32_t au0 = (uint32_t)__shfl((int)u0, srcA);
      uint32_t av0 = (uint32_t)__shfl((int)v0, srcA);
      uint32_t au1 = (uint32_t)__shfl((int)u1, srcA);
      uint32_t av1 = (uint32_t)__shfl((int)v1, srcA);
      uint32_t bu0 = (uint32_t)__shfl((int)u0, srcB);
      uint32_t bv0 = (uint32_t)__shfl((int)v0, srcB);
      uint32_t bu1 = (uint32_t)__shfl((int)u1, srcB);
      uint32_t bv1 = (uint32_t)__shfl((int)v1, srcB);
      union { uint32_t u[4]; bf16x8 v; } pb;
      pb.u[0] = stsel ? au1 : au0;
      pb.u[1] = stsel ? av1 : av0;
      pb.u[2] = stsel ? bu1 : bu0;
      pb.u[3] = stsel ? bv1 : bv0;
#pragma unroll
      for (int dt = 0; dt < 4; ++dt) {
        bf16x8 va = *(const bf16x8*)(Vt + (dt * 16 + l16) * VTS +
                                     jc * 32 + quad * 8);
        oacc[dt] = mfma16(va, pb.v, oacc[dt]);
      }
    }

    // O store via per-wave LDS bounce -> full 128B line stores
#pragma unroll
    for (int dt = 0; dt < 4; ++dt) {
      ushort4 pk;
      pk.x = f2bf(oacc[dt][0] * inv);
      pk.y = f2bf(oacc[dt][1] * inv);
      pk.z = f2bf(oacc[dt][2] * inv);
      pk.w = f2bf(oacc[dt][3] * inv);
      *(ushort4*)(ob + l16 * OBS + dt * 16 + quad * 4) = pk;
    }
    __asm__ __volatile__("s_waitcnt lgkmcnt(0)" ::: "memory");
#pragma unroll
    for (int rnd = 0; rnd < 4; ++rnd) {
      int q   = rnd * 4 + (lane >> 4);
      int o8  = lane & 15;
      uint2 d8 = *(const uint2*)(ob + q * OBS + o8 * 4);
      int qrow = mt * 16 + q;
      if (qrow < NTOK) {
        size_t obase = (size_t)(b * NTOK + qrow) * DIMC + h * HDIM;
        *(uint2*)(aout + obase + o8 * 4) = d8;
      }
    }
  }
}

// ---------------- launcher ----------------
extern "C" void kernel_launch(void* const* d_in, const int* in_sizes, int n_in,
                              void* d_out, int out_size, void* d_ws, size_t ws_size,
                              hipStream_t stream) {
  const float* x     = (const float*)d_in[0];
  const float* scale = (const float*)d_in[1];
  const float* wqkv  = (const float*)d_in[2];
  const float* wproj = (const float*)d_in[3];
  const float* bproj = (const float*)d_in[4];
  float* out = (float*)d_out;

  // ws layout (ushort), ~82.2 MB (R6-proven). attb aliases xb.
  unsigned short* xb   = (unsigned short*)d_ws;
  unsigned short* wqb  = xb  + (size_t)MTOK * DIMC;
  unsigned short* wpb  = wqb + (size_t)QKVO * DIMC;
  unsigned short* qkvb = wpb + (size_t)DIMC * DIMC;
  unsigned short* attb = xb;                          // alias

  cvt_all<<<CVNB, 256, 0, stream>>>(x, wqkv, wproj, xb, wqb, wpb);
  // QK part: output channels [0, 1536) -> 12 N-tiles
  gemm_qkv_part<<<GM * 12, 256, 0, stream>>>(xb, wqb, qkvb, 0, 12);
  // V part: output channels [1536, 2304) -> 6 N-tiles
  gemm_qkv_part<<<GM * 6, 256, 0, stream>>>(xb, wqb, qkvb, 12, 6);
  attn_fused<<<BH, 256, 0, stream>>>(qkvb, scale, attb);
  gemm_proj<<<GM * (DIMC / 128), 256, 0, stream>>>(attb, wpb, bproj, x, out);
}

// Round 10
// 216.378 us; speedup vs baseline: 1.9077x; 1.1068x over previous
//
#include <hip/hip_runtime.h>
#include <cstdint>
#include <cstddef>

#define DEV static __device__ __forceinline__

typedef __attribute__((ext_vector_type(8))) short bf16x8;   // 8 bf16 (4 VGPRs)
typedef __attribute__((ext_vector_type(4))) float f32x4;

constexpr int NB   = 64;     // batch
constexpr int NTOK = 197;    // tokens
constexpr int DIMC = 768;    // channels
constexpr int NH   = 12;     // heads
constexpr int HDIM = 64;     // head dim
constexpr int MTOK = NB * NTOK;   // 12608 rows
constexpr int QKVO = 3 * DIMC;    // 2304
constexpr int BH   = NB * NH;     // 768
constexpr int KROWS = 198;        // staged K rows (jrow clamped to 197)
constexpr int VTS   = 232;        // V^T row stride (464B, 16B-aligned)
constexpr int OBS   = 68;         // O-bounce row stride (136B)
constexpr int GM    = (MTOK + 127) / 128;   // 99 M-tiles (128-row)
constexpr int GM64  = MTOK / 64;            // 197 M-tiles (64-row, exact)

DEV unsigned short f2bf(float f) {
  union { float f; uint32_t u; } v; v.f = f;
  uint32_t u = v.u;
  return (unsigned short)((u + 0x7FFFu + ((u >> 16) & 1u)) >> 16);  // RNE, finite
}

DEV uint32_t pack_bf2(float a, float b) {
  return (uint32_t)f2bf(a) | ((uint32_t)f2bf(b) << 16);
}

DEV f32x4 mfma16(bf16x8 a, bf16x8 b, f32x4 c) {
  return __builtin_amdgcn_mfma_f32_16x16x32_bf16(a, b, c, 0, 0, 0);
}

DEV void async_cp16(const unsigned short* g, unsigned short* l) {
  __builtin_amdgcn_global_load_lds(
      (__attribute__((address_space(1))) void*)g,
      (__attribute__((address_space(3))) void*)l, 16, 0, 0);
}

// supertile swizzle (tile-index form): groups of 8 M-tiles, N-major inside.
DEV void swizzle_idx(int lin, int gridM, int gridN, int& mt, int& nt) {
  int per = 8 * gridN;
  int sup = lin / per;
  int bm  = sup * 8;
  int Gm  = gridM - bm; if (Gm > 8) Gm = 8;
  int rem = lin - sup * per;
  nt = rem / Gm;
  mt = bm + (rem - nt * Gm);
}

// ---------------- f32 -> bf16 converts: one kernel, 4 float4/thread ----------------
constexpr int CVB1 = (MTOK * DIMC) / 4096;   // 2364
constexpr int CVB2 = (QKVO * DIMC) / 4096;   //  432
constexpr int CVB3 = (DIMC * DIMC) / 4096;   //  144
constexpr int CVNB = CVB1 + CVB2 + CVB3;     // 2940

__global__ void __launch_bounds__(256) cvt_all(const float* __restrict__ x,
                                               const float* __restrict__ wq,
                                               const float* __restrict__ wp,
                                               unsigned short* __restrict__ xb,
                                               unsigned short* __restrict__ wqb,
                                               unsigned short* __restrict__ wpb) {
  int blk = blockIdx.x;
  const float* s; unsigned short* d;
  if (blk < CVB1)               { s = x;  d = xb; }
  else if (blk < CVB1 + CVB2)   { s = wq; d = wqb; blk -= CVB1; }
  else                          { s = wp; d = wpb; blk -= CVB1 + CVB2; }
  size_t base = (size_t)blk * 4096 + (size_t)threadIdx.x * 4;
#pragma unroll
  for (int j = 0; j < 4; ++j) {
    size_t i = base + (size_t)j * 1024;
    float4 f = *(const float4*)(s + i);
    ushort4 o;
    o.x = f2bf(f.x); o.y = f2bf(f.y); o.z = f2bf(f.z); o.w = f2bf(f.w);
    *(ushort4*)(d + i) = o;
  }
}

// ---------------- QKV GEMM: 128x128 tiles -> qkv bf16 [3][B][H][N][HD] ----------------
__global__ void __launch_bounds__(256) gemm_qkv(const unsigned short* __restrict__ A,
                                                const unsigned short* __restrict__ Bw,
                                                unsigned short* __restrict__ qkv) {
  __shared__ __align__(16) unsigned short As[128 * 64];
  __shared__ __align__(16) unsigned short Bs[128 * 64];
  const int tid = threadIdx.x, lane = tid & 63, wave = tid >> 6;
  const int wm = wave & 1, wn = wave >> 1;
  const int l16 = lane & 15, quad = lane >> 4;
  int mt, nt;
  swizzle_idx(blockIdx.x, GM, QKVO / 128, mt, nt);
  const int mbase = mt * 128, nbase = nt * 128;

  f32x4 acc[4][4];
#pragma unroll
  for (int i = 0; i < 4; ++i)
#pragma unroll
    for (int j = 0; j < 4; ++j) acc[i][j] = {0.f, 0.f, 0.f, 0.f};

  for (int k0 = 0; k0 < DIMC; k0 += 64) {
#pragma unroll
    for (int i = 0; i < 4; ++i) {
      int c = i * 256 + tid;
      int row = c >> 3, cc = c & 7;
      int gc = (cc ^ (row & 7)) * 8;
      int ar = mbase + row; ar = ar < MTOK ? ar : MTOK - 1;   // M tail clamp
      async_cp16(A  + (size_t)ar * DIMC + k0 + gc, As + c * 8);
      async_cp16(Bw + (size_t)(nbase + row) * DIMC + k0 + gc, Bs + c * 8);
    }
    __syncthreads();
#pragma unroll
    for (int kk = 0; kk < 64; kk += 32) {
      const int cw = (kk >> 3) + quad;
      bf16x8 af[4], bfr[4];
#pragma unroll
      for (int mi = 0; mi < 4; ++mi) {
        int r = wm * 64 + mi * 16 + l16;
        af[mi] = *(const bf16x8*)(As + r * 64 + (cw ^ (r & 7)) * 8);
      }
#pragma unroll
      for (int ni = 0; ni < 4; ++ni) {
        int r = wn * 64 + ni * 16 + l16;
        bfr[ni] = *(const bf16x8*)(Bs + r * 64 + (cw ^ (r & 7)) * 8);
      }
#pragma unroll
      for (int mi = 0; mi < 4; ++mi)
#pragma unroll
        for (int ni = 0; ni < 4; ++ni)
          acc[mi][ni] = mfma16(af[mi], bfr[ni], acc[mi][ni]);
    }
    __syncthreads();
  }

  const int oc64  = nbase + wn * 64;   // 64-aligned -> uniform which/h
  const int which = oc64 / DIMC;
  const int h     = (oc64 % DIMC) / HDIM;
#pragma unroll
  for (int mi = 0; mi < 4; ++mi) {
    int t0 = mbase + wm * 64 + mi * 16 + quad * 4;
#pragma unroll
    for (int r = 0; r < 4; ++r) {
      int t = t0 + r;
      if (t < MTOK) {
        int b = t / NTOK, n = t - b * NTOK;
        size_t base = ((size_t)((which * NB + b) * NH + h) * NTOK + n) * HDIM;
#pragma unroll
        for (int ni = 0; ni < 4; ++ni)
          qkv[base + ni * 16 + l16] = f2bf(acc[mi][ni][r]);
      }
    }
  }
}

// ---------------- Proj GEMM 64x128 tiles (+bias+residual, fp32 out) ----------------
// 1182 blocks (vs 594 at 128^2): ~6 blocks/CU by LDS (24KB) so staging-barrier
// stalls overlap across blocks. R9 counters: 128^2 proj ran at Occupancy 12%,
// MfmaUtil 11%, 1.69 TB/s -- latency-bound from 2.3 blocks/CU.
__global__ void __launch_bounds__(256) gemm_proj(const unsigned short* __restrict__ A,
                                                 const unsigned short* __restrict__ Bw,
                                                 const float* __restrict__ bias,
                                                 const float* __restrict__ xres,
                                                 float* __restrict__ out) {
  __shared__ __align__(16) unsigned short As[64 * 64];    //  8 KB
  __shared__ __align__(16) unsigned short Bs[128 * 64];   // 16 KB
  const int tid = threadIdx.x, lane = tid & 63, wave = tid >> 6;
  const int wm = wave & 1, wn = wave >> 1;
  const int l16 = lane & 15, quad = lane >> 4;
  int mt, nt;
  swizzle_idx(blockIdx.x, GM64, DIMC / 128, mt, nt);
  const int mbase = mt * 64, nbase = nt * 128;   // MTOK = 197*64 exactly: no tail

  f32x4 acc[2][4];
#pragma unroll
  for (int i = 0; i < 2; ++i)
#pragma unroll
    for (int j = 0; j < 4; ++j) acc[i][j] = {0.f, 0.f, 0.f, 0.f};

  for (int k0 = 0; k0 < DIMC; k0 += 64) {
#pragma unroll
    for (int i = 0; i < 2; ++i) {          // A: 512 x 16B chunks
      int c = i * 256 + tid;
      int row = c >> 3, cc = c & 7;
      int gc = (cc ^ (row & 7)) * 8;
      async_cp16(A + (size_t)(mbase + row) * DIMC + k0 + gc, As + c * 8);
    }
#pragma unroll
    for (int i = 0; i < 4; ++i) {          // B: 1024 x 16B chunks
      int c = i * 256 + tid;
      int row = c >> 3, cc = c & 7;
      int gc = (cc ^ (row & 7)) * 8;
      async_cp16(Bw + (size_t)(nbase + row) * DIMC + k0 + gc, Bs + c * 8);
    }
    __syncthreads();
#pragma unroll
    for (int kk = 0; kk < 64; kk += 32) {
      const int cw = (kk >> 3) + quad;
      bf16x8 af[2], bfr[4];
#pragma unroll
      for (int mi = 0; mi < 2; ++mi) {
        int r = wm * 32 + mi * 16 + l16;
        af[mi] = *(const bf16x8*)(As + r * 64 + (cw ^ (r & 7)) * 8);
      }
#pragma unroll
      for (int ni = 0; ni < 4; ++ni) {
        int r = wn * 64 + ni * 16 + l16;
        bfr[ni] = *(const bf16x8*)(Bs + r * 64 + (cw ^ (r & 7)) * 8);
      }
#pragma unroll
      for (int mi = 0; mi < 2; ++mi)
#pragma unroll
        for (int ni = 0; ni < 4; ++ni)
          acc[mi][ni] = mfma16(af[mi], bfr[ni], acc[mi][ni]);
    }
    __syncthreads();
  }

  const int oc = nbase + wn * 64;
#pragma unroll
  for (int mi = 0; mi < 2; ++mi) {
    int t0 = mbase + wm * 32 + mi * 16 + quad * 4;
#pragma unroll
    for (int r = 0; r < 4; ++r) {
      int t = t0 + r;                      // always < MTOK (exact tiling)
      size_t rowb = (size_t)t * DIMC;
#pragma unroll
      for (int ni = 0; ni < 4; ++ni) {
        int o = oc + ni * 16 + l16;
        out[rowb + o] = acc[mi][ni][r] + bias[o] + xres[rowb + o];
      }
    }
  }
}

// ---------------- fused attention: 768 blocks x 1 head (R6-proven) ----------------
__global__ void __launch_bounds__(256, 2) attn_fused(const unsigned short* __restrict__ qkv,
                                                     const float* __restrict__ scale,
                                                     unsigned short* __restrict__ aout) {
  __shared__ __align__(16) unsigned short Ks[KROWS * 64];        // 25344 B
  __shared__ __align__(16) unsigned short Vt[HDIM * VTS];        // 29696 B
  __shared__ __align__(16) unsigned short Ob[4 * 16 * OBS];      //  8704 B

  const int tid = threadIdx.x, lane = tid & 63, wave = tid >> 6;
  const int l16 = lane & 15, quad = lane >> 4;
  const int bh = blockIdx.x;
  const int b = bh / NH, h = bh - b * NH;

  const unsigned short* qg = qkv + (size_t)bh * (NTOK * HDIM);
  const unsigned short* kg = qkv + (size_t)(BH + bh) * (NTOK * HDIM);
  const unsigned short* vg = qkv + (size_t)(2 * BH + bh) * (NTOK * HDIM);
  const float sc = scale[h];

  // stage K via DMA: rows 0..197
#pragma unroll
  for (int i = 0; i < 7; ++i) {
    int c = i * 256 + tid;
    if (c < KROWS * 8) {
      int row = c >> 3, cc = c & 7;
      async_cp16(kg + (size_t)row * 64 + ((cc ^ (row & 7)) * 8), Ks + c * 8);
    }
  }
  // build V^T: coalesced 128B row reads + b128 writes at stride VTS
  {
    const int dcol = tid & 63;
    const int slab = tid >> 6;
#pragma unroll
    for (int p = 0; p < 7; ++p) {
      int n0 = p * 32 + slab * 8;
      union { unsigned short us[8]; bf16x8 v; } tr;
#pragma unroll
      for (int i = 0; i < 8; ++i) {
        int n = n0 + i; n = n > NTOK - 1 ? NTOK - 1 : n;
        tr.us[i] = vg[(size_t)n * HDIM + dcol];
      }
      *(bf16x8*)(Vt + dcol * VTS + n0) = tr.v;
    }
  }
  __syncthreads();

  const int srcA  = l16 + ((quad & 1) << 5);
  const int srcB  = srcA + 16;
  const int stsel = quad >> 1;
  unsigned short* ob = Ob + wave * (16 * OBS);

  for (int mt = wave; mt < 13; mt += 4) {
    int qr = mt * 16 + l16; if (qr > NTOK - 1) qr = NTOK - 1;
    bf16x8 qb0 = *(const bf16x8*)(qg + (size_t)qr * 64 + quad * 8);
    bf16x8 qb1 = *(const bf16x8*)(qg + (size_t)qr * 64 + 32 + quad * 8);
    const int mg = mt * 16 + l16;

    // batched S^T = K.Q^T (26 MFMAs; jc=6,st=1 keys all masked)
    f32x4 s[7][2];
#pragma unroll
    for (int jc = 0; jc < 7; ++jc)
#pragma unroll
      for (int st = 0; st < 2; ++st) {
        if (jc == 6 && st == 1) { s[6][1] = {0.f, 0.f, 0.f, 0.f}; continue; }
        int jrow = (jc * 2 + st) * 16 + l16;
        jrow = jrow > NTOK ? NTOK : jrow;
        const unsigned short* kr = Ks + jrow * 64;
        bf16x8 ka0 = *(const bf16x8*)(kr + (quad       ^ (jrow & 7)) * 8);
        bf16x8 ka1 = *(const bf16x8*)(kr + ((4 + quad) ^ (jrow & 7)) * 8);
        f32x4 t = {0.f, 0.f, 0.f, 0.f};
        t = mfma16(ka0, qb0, t);
        t = mfma16(ka1, qb1, t);
        s[jc][st] = t;
      }

    // softmax over keys (row = l16)
    float cmax = -1e30f;
#pragma unroll
    for (int jc = 0; jc < 7; ++jc)
#pragma unroll
      for (int st = 0; st < 2; ++st)
#pragma unroll
        for (int r = 0; r < 4; ++r) {
          int jg = jc * 32 + st * 16 + quad * 4 + r;
          float v = s[jc][st][r] * sc;
          v = (jg >= NTOK || jg == mg) ? -1e30f : v;
          s[jc][st][r] = v;
          cmax = fmaxf(cmax, v);
        }
    cmax = fmaxf(cmax, __shfl_xor(cmax, 16));
    cmax = fmaxf(cmax, __shfl_xor(cmax, 32));
    float psum = 0.f;
#pragma unroll
    for (int jc = 0; jc < 7; ++jc)
#pragma unroll
      for (int st = 0; st < 2; ++st)
#pragma unroll
        for (int r = 0; r < 4; ++r) {
          float e = __expf(s[jc][st][r] - cmax);
          psum += e;
          s[jc][st][r] = e;
        }
    psum += __shfl_xor(psum, 16);
    psum += __shfl_xor(psum, 32);
    const float inv = 1.0f / psum;

    // PV: O^T = V^T.P^T; P^T B-frags via shfl, V^T b128 from LDS
    f32x4 oacc[4];
#pragma unroll
    for (int dt = 0; dt < 4; ++dt) oacc[dt] = {0.f, 0.f, 0.f, 0.f};

#pragma unroll
    for (int jc = 0; jc < 7; ++jc) {
      uint32_t u0 = pack_bf2(s[jc][0][0], s[jc][0][1]);
      uint32_t v0 = pack_bf2(s[jc][0][2], s[jc][0][3]);
      uint32_t u1 = pack_bf2(s[jc][1][0], s[jc][1][1]);
      uint32_t v1 = pack_bf2(s[jc][1][2], s[jc][1][3]);
      uint32_t au0 = (uint32_t)__shfl((int)u0, srcA);
      uint32_t av0 = (uint32_t)__shfl((int)v0, srcA);
      uint32_t au1 = (uint32_t)__shfl((int)u1, srcA);
      uint32_t av1 = (uint32_t)__shfl((int)v1, srcA);
      uint32_t bu0 = (uint32_t)__shfl((int)u0, srcB);
      uint32_t bv0 = (uint32_t)__shfl((int)v0, srcB);
      uint32_t bu1 = (uint32_t)__shfl((int)u1, srcB);
      uint32_t bv1 = (uint32_t)__shfl((int)v1, srcB);
      union { uint32_t u[4]; bf16x8 v; } pb;
      pb.u[0] = stsel ? au1 : au0;
      pb.u[1] = stsel ? av1 : av0;
      pb.u[2] = stsel ? bu1 : bu0;
      pb.u[3] = stsel ? bv1 : bv0;
#pragma unroll
      for (int dt = 0; dt < 4; ++dt) {
        bf16x8 va = *(const bf16x8*)(Vt + (dt * 16 + l16) * VTS +
                                     jc * 32 + quad * 8);
        oacc[dt] = mfma16(va, pb.v, oacc[dt]);
      }
    }

    // O store via per-wave LDS bounce -> full 128B line stores
#pragma unroll
    for (int dt = 0; dt < 4; ++dt) {
      ushort4 pk;
      pk.x = f2bf(oacc[dt][0] * inv);
      pk.y = f2bf(oacc[dt][1] * inv);
      pk.z = f2bf(oacc[dt][2] * inv);
      pk.w = f2bf(oacc[dt][3] * inv);
      *(ushort4*)(ob + l16 * OBS + dt * 16 + quad * 4) = pk;
    }
    __asm__ __volatile__("s_waitcnt lgkmcnt(0)" ::: "memory");
#pragma unroll
    for (int rnd = 0; rnd < 4; ++rnd) {
      int q   = rnd * 4 + (lane >> 4);
      int o8  = lane & 15;
      uint2 d8 = *(const uint2*)(ob + q * OBS + o8 * 4);
      int qrow = mt * 16 + q;
      if (qrow < NTOK) {
        size_t obase = (size_t)(b * NTOK + qrow) * DIMC + h * HDIM;
        *(uint2*)(aout + obase + o8 * 4) = d8;
      }
    }
  }
}

// ---------------- launcher ----------------
extern "C" void kernel_launch(void* const* d_in, const int* in_sizes, int n_in,
                              void* d_out, int out_size, void* d_ws, size_t ws_size,
                              hipStream_t stream) {
  const float* x     = (const float*)d_in[0];
  const float* scale = (const float*)d_in[1];
  const float* wqkv  = (const float*)d_in[2];
  const float* wproj = (const float*)d_in[3];
  const float* bproj = (const float*)d_in[4];
  float* out = (float*)d_out;

  // ws layout (ushort), ~82.2 MB (R6-proven). attb aliases xb.
  unsigned short* xb   = (unsigned short*)d_ws;
  unsigned short* wqb  = xb  + (size_t)MTOK * DIMC;
  unsigned short* wpb  = wqb + (size_t)QKVO * DIMC;
  unsigned short* qkvb = wpb + (size_t)DIMC * DIMC;
  unsigned short* attb = xb;                          // alias

  cvt_all<<<CVNB, 256, 0, stream>>>(x, wqkv, wproj, xb, wqb, wpb);
  gemm_qkv<<<GM * (QKVO / 128), 256, 0, stream>>>(xb, wqb, qkvb);
  attn_fused<<<BH, 256, 0, stream>>>(qkvb, scale, attb);
  gemm_proj<<<GM64 * (DIMC / 128), 256, 0, stream>>>(attb, wpb, bproj, x, out);
}

// Round 11
// 215.215 us; speedup vs baseline: 1.9180x; 1.0054x over previous
//
#include <hip/hip_runtime.h>
#include <cstdint>
#include <cstddef>

#define DEV static __device__ __forceinline__

typedef __attribute__((ext_vector_type(8))) short bf16x8;   // 8 bf16 (4 VGPRs)
typedef __attribute__((ext_vector_type(4))) float f32x4;

constexpr int NB   = 64;     // batch
constexpr int NTOK = 197;    // tokens
constexpr int DIMC = 768;    // channels
constexpr int NH   = 12;     // heads
constexpr int HDIM = 64;     // head dim
constexpr int MTOK = NB * NTOK;   // 12608 rows
constexpr int QKVO = 3 * DIMC;    // 2304
constexpr int BH   = NB * NH;     // 768
constexpr int KROWS = 198;        // staged K rows (jrow clamped to 197)
constexpr int VTS   = 232;        // V^T row stride (464B, 16B-aligned)
constexpr int OBS   = 68;         // O-bounce row stride (136B)
constexpr int GM    = (MTOK + 127) / 128;   // 99 M-tiles (128-row)
constexpr int GM64  = MTOK / 64;            // 197 M-tiles (64-row, exact)

DEV unsigned short f2bf(float f) {
  union { float f; uint32_t u; } v; v.f = f;
  uint32_t u = v.u;
  return (unsigned short)((u + 0x7FFFu + ((u >> 16) & 1u)) >> 16);  // RNE, finite
}

DEV uint32_t pack_bf2(float a, float b) {
  return (uint32_t)f2bf(a) | ((uint32_t)f2bf(b) << 16);
}

DEV f32x4 mfma16(bf16x8 a, bf16x8 b, f32x4 c) {
  return __builtin_amdgcn_mfma_f32_16x16x32_bf16(a, b, c, 0, 0, 0);
}

DEV void async_cp16(const unsigned short* g, unsigned short* l) {
  __builtin_amdgcn_global_load_lds(
      (__attribute__((address_space(1))) void*)g,
      (__attribute__((address_space(3))) void*)l, 16, 0, 0);
}

// supertile swizzle: groups of 16 M-tiles, N-major inside the group.
// Gm=16 (was 8): halves the number of full-B sweeps (13 -> 7 supers for
// GM=99), cutting B re-fetch ~46 -> ~25 MB while the A band (16 x 1.5KB x
// 128 rows = 3 MB) still fits one XCD's 4 MB L2. [R10 FETCH showed B
// re-reads dominate qkv's 54 MB vs 23 ideal.]
DEV void swizzle_idx(int lin, int gridM, int gridN, int& mt, int& nt) {
  int per = 16 * gridN;
  int sup = lin / per;
  int bm  = sup * 16;
  int Gm  = gridM - bm; if (Gm > 16) Gm = 16;
  int rem = lin - sup * per;
  nt = rem / Gm;
  mt = bm + (rem - nt * Gm);
}

// ---------------- f32 -> bf16 converts: one kernel, 4 float4/thread ----------------
constexpr int CVB1 = (MTOK * DIMC) / 4096;   // 2364
constexpr int CVB2 = (QKVO * DIMC) / 4096;   //  432
constexpr int CVB3 = (DIMC * DIMC) / 4096;   //  144
constexpr int CVNB = CVB1 + CVB2 + CVB3;     // 2940

__global__ void __launch_bounds__(256) cvt_all(const float* __restrict__ x,
                                               const float* __restrict__ wq,
                                               const float* __restrict__ wp,
                                               unsigned short* __restrict__ xb,
                                               unsigned short* __restrict__ wqb,
                                               unsigned short* __restrict__ wpb) {
  int blk = blockIdx.x;
  const float* s; unsigned short* d;
  if (blk < CVB1)               { s = x;  d = xb; }
  else if (blk < CVB1 + CVB2)   { s = wq; d = wqb; blk -= CVB1; }
  else                          { s = wp; d = wpb; blk -= CVB1 + CVB2; }
  size_t base = (size_t)blk * 4096 + (size_t)threadIdx.x * 4;
#pragma unroll
  for (int j = 0; j < 4; ++j) {
    size_t i = base + (size_t)j * 1024;
    float4 f = *(const float4*)(s + i);
    ushort4 o;
    o.x = f2bf(f.x); o.y = f2bf(f.y); o.z = f2bf(f.z); o.w = f2bf(f.w);
    *(ushort4*)(d + i) = o;
  }
}

// ---------------- QKV GEMM: 128x128 tiles -> qkv bf16 [3][B][H][N][HD] ----------------
__global__ void __launch_bounds__(256) gemm_qkv(const unsigned short* __restrict__ A,
                                                const unsigned short* __restrict__ Bw,
                                                unsigned short* __restrict__ qkv) {
  __shared__ __align__(16) unsigned short As[128 * 64];
  __shared__ __align__(16) unsigned short Bs[128 * 64];
  const int tid = threadIdx.x, lane = tid & 63, wave = tid >> 6;
  const int wm = wave & 1, wn = wave >> 1;
  const int l16 = lane & 15, quad = lane >> 4;
  int mt, nt;
  swizzle_idx(blockIdx.x, GM, QKVO / 128, mt, nt);
  const int mbase = mt * 128, nbase = nt * 128;

  f32x4 acc[4][4];
#pragma unroll
  for (int i = 0; i < 4; ++i)
#pragma unroll
    for (int j = 0; j < 4; ++j) acc[i][j] = {0.f, 0.f, 0.f, 0.f};

  for (int k0 = 0; k0 < DIMC; k0 += 64) {
#pragma unroll
    for (int i = 0; i < 4; ++i) {
      int c = i * 256 + tid;
      int row = c >> 3, cc = c & 7;
      int gc = (cc ^ (row & 7)) * 8;
      int ar = mbase + row; ar = ar < MTOK ? ar : MTOK - 1;   // M tail clamp
      async_cp16(A  + (size_t)ar * DIMC + k0 + gc, As + c * 8);
      async_cp16(Bw + (size_t)(nbase + row) * DIMC + k0 + gc, Bs + c * 8);
    }
    __syncthreads();
#pragma unroll
    for (int kk = 0; kk < 64; kk += 32) {
      const int cw = (kk >> 3) + quad;
      bf16x8 af[4], bfr[4];
#pragma unroll
      for (int mi = 0; mi < 4; ++mi) {
        int r = wm * 64 + mi * 16 + l16;
        af[mi] = *(const bf16x8*)(As + r * 64 + (cw ^ (r & 7)) * 8);
      }
#pragma unroll
      for (int ni = 0; ni < 4; ++ni) {
        int r = wn * 64 + ni * 16 + l16;
        bfr[ni] = *(const bf16x8*)(Bs + r * 64 + (cw ^ (r & 7)) * 8);
      }
#pragma unroll
      for (int mi = 0; mi < 4; ++mi)
#pragma unroll
        for (int ni = 0; ni < 4; ++ni)
          acc[mi][ni] = mfma16(af[mi], bfr[ni], acc[mi][ni]);
    }
    __syncthreads();
  }

  const int oc64  = nbase + wn * 64;   // 64-aligned -> uniform which/h
  const int which = oc64 / DIMC;
  const int h     = (oc64 % DIMC) / HDIM;
#pragma unroll
  for (int mi = 0; mi < 4; ++mi) {
    int t0 = mbase + wm * 64 + mi * 16 + quad * 4;
#pragma unroll
    for (int r = 0; r < 4; ++r) {
      int t = t0 + r;
      if (t < MTOK) {
        int b = t / NTOK, n = t - b * NTOK;
        size_t base = ((size_t)((which * NB + b) * NH + h) * NTOK + n) * HDIM;
#pragma unroll
        for (int ni = 0; ni < 4; ++ni)
          qkv[base + ni * 16 + l16] = f2bf(acc[mi][ni][r]);
      }
    }
  }
}

// ---------------- Proj GEMM 64x128 tiles (+bias+residual, fp32 out) ----------------
// 1182 blocks, 24KB LDS -> ~5 blocks/CU: staging-barrier stalls overlap
// across blocks (R9's 128^2 proj: 12% occupancy, 47us; R10 64x128: <73us).
__global__ void __launch_bounds__(256) gemm_proj(const unsigned short* __restrict__ A,
                                                 const unsigned short* __restrict__ Bw,
                                                 const float* __restrict__ bias,
                                                 const float* __restrict__ xres,
                                                 float* __restrict__ out) {
  __shared__ __align__(16) unsigned short As[64 * 64];    //  8 KB
  __shared__ __align__(16) unsigned short Bs[128 * 64];   // 16 KB
  const int tid = threadIdx.x, lane = tid & 63, wave = tid >> 6;
  const int wm = wave & 1, wn = wave >> 1;
  const int l16 = lane & 15, quad = lane >> 4;
  int mt, nt;
  swizzle_idx(blockIdx.x, GM64, DIMC / 128, mt, nt);
  const int mbase = mt * 64, nbase = nt * 128;   // MTOK = 197*64 exactly: no tail

  f32x4 acc[2][4];
#pragma unroll
  for (int i = 0; i < 2; ++i)
#pragma unroll
    for (int j = 0; j < 4; ++j) acc[i][j] = {0.f, 0.f, 0.f, 0.f};

  for (int k0 = 0; k0 < DIMC; k0 += 64) {
#pragma unroll
    for (int i = 0; i < 2; ++i) {          // A: 512 x 16B chunks
      int c = i * 256 + tid;
      int row = c >> 3, cc = c & 7;
      int gc = (cc ^ (row & 7)) * 8;
      async_cp16(A + (size_t)(mbase + row) * DIMC + k0 + gc, As + c * 8);
    }
#pragma unroll
    for (int i = 0; i < 4; ++i) {          // B: 1024 x 16B chunks
      int c = i * 256 + tid;
      int row = c >> 3, cc = c & 7;
      int gc = (cc ^ (row & 7)) * 8;
      async_cp16(Bw + (size_t)(nbase + row) * DIMC + k0 + gc, Bs + c * 8);
    }
    __syncthreads();
#pragma unroll
    for (int kk = 0; kk < 64; kk += 32) {
      const int cw = (kk >> 3) + quad;
      bf16x8 af[2], bfr[4];
#pragma unroll
      for (int mi = 0; mi < 2; ++mi) {
        int r = wm * 32 + mi * 16 + l16;
        af[mi] = *(const bf16x8*)(As + r * 64 + (cw ^ (r & 7)) * 8);
      }
#pragma unroll
      for (int ni = 0; ni < 4; ++ni) {
        int r = wn * 64 + ni * 16 + l16;
        bfr[ni] = *(const bf16x8*)(Bs + r * 64 + (cw ^ (r & 7)) * 8);
      }
#pragma unroll
      for (int mi = 0; mi < 2; ++mi)
#pragma unroll
        for (int ni = 0; ni < 4; ++ni)
          acc[mi][ni] = mfma16(af[mi], bfr[ni], acc[mi][ni]);
    }
    __syncthreads();
  }

  const int oc = nbase + wn * 64;
#pragma unroll
  for (int mi = 0; mi < 2; ++mi) {
    int t0 = mbase + wm * 32 + mi * 16 + quad * 4;
#pragma unroll
    for (int r = 0; r < 4; ++r) {
      int t = t0 + r;                      // always < MTOK (exact tiling)
      size_t rowb = (size_t)t * DIMC;
#pragma unroll
      for (int ni = 0; ni < 4; ++ni) {
        int o = oc + ni * 16 + l16;
        out[rowb + o] = acc[mi][ni][r] + bias[o] + xres[rowb + o];
      }
    }
  }
}

// ---------------- fused attention: 768 blocks x 1 head (R6-proven) ----------------
__global__ void __launch_bounds__(256, 2) attn_fused(const unsigned short* __restrict__ qkv,
                                                     const float* __restrict__ scale,
                                                     unsigned short* __restrict__ aout) {
  __shared__ __align__(16) unsigned short Ks[KROWS * 64];        // 25344 B
  __shared__ __align__(16) unsigned short Vt[HDIM * VTS];        // 29696 B
  __shared__ __align__(16) unsigned short Ob[4 * 16 * OBS];      //  8704 B

  const int tid = threadIdx.x, lane = tid & 63, wave = tid >> 6;
  const int l16 = lane & 15, quad = lane >> 4;
  const int bh = blockIdx.x;
  const int b = bh / NH, h = bh - b * NH;

  const unsigned short* qg = qkv + (size_t)bh * (NTOK * HDIM);
  const unsigned short* kg = qkv + (size_t)(BH + bh) * (NTOK * HDIM);
  const unsigned short* vg = qkv + (size_t)(2 * BH + bh) * (NTOK * HDIM);
  const float sc = scale[h];

  // stage K via DMA: rows 0..197
#pragma unroll
  for (int i = 0; i < 7; ++i) {
    int c = i * 256 + tid;
    if (c < KROWS * 8) {
      int row = c >> 3, cc = c & 7;
      async_cp16(kg + (size_t)row * 64 + ((cc ^ (row & 7)) * 8), Ks + c * 8);
    }
  }
  // build V^T: coalesced 128B row reads + b128 writes at stride VTS
  {
    const int dcol = tid & 63;
    const int slab = tid >> 6;
#pragma unroll
    for (int p = 0; p < 7; ++p) {
      int n0 = p * 32 + slab * 8;
      union { unsigned short us[8]; bf16x8 v; } tr;
#pragma unroll
      for (int i = 0; i < 8; ++i) {
        int n = n0 + i; n = n > NTOK - 1 ? NTOK - 1 : n;
        tr.us[i] = vg[(size_t)n * HDIM + dcol];
      }
      *(bf16x8*)(Vt + dcol * VTS + n0) = tr.v;
    }
  }
  __syncthreads();

  const int srcA  = l16 + ((quad & 1) << 5);
  const int srcB  = srcA + 16;
  const int stsel = quad >> 1;
  unsigned short* ob = Ob + wave * (16 * OBS);

  for (int mt = wave; mt < 13; mt += 4) {
    int qr = mt * 16 + l16; if (qr > NTOK - 1) qr = NTOK - 1;
    bf16x8 qb0 = *(const bf16x8*)(qg + (size_t)qr * 64 + quad * 8);
    bf16x8 qb1 = *(const bf16x8*)(qg + (size_t)qr * 64 + 32 + quad * 8);
    const int mg = mt * 16 + l16;

    // batched S^T = K.Q^T (26 MFMAs; jc=6,st=1 keys all masked)
    f32x4 s[7][2];
#pragma unroll
    for (int jc = 0; jc < 7; ++jc)
#pragma unroll
      for (int st = 0; st < 2; ++st) {
        if (jc == 6 && st == 1) { s[6][1] = {0.f, 0.f, 0.f, 0.f}; continue; }
        int jrow = (jc * 2 + st) * 16 + l16;
        jrow = jrow > NTOK ? NTOK : jrow;
        const unsigned short* kr = Ks + jrow * 64;
        bf16x8 ka0 = *(const bf16x8*)(kr + (quad       ^ (jrow & 7)) * 8);
        bf16x8 ka1 = *(const bf16x8*)(kr + ((4 + quad) ^ (jrow & 7)) * 8);
        f32x4 t = {0.f, 0.f, 0.f, 0.f};
        t = mfma16(ka0, qb0, t);
        t = mfma16(ka1, qb1, t);
        s[jc][st] = t;
      }

    // softmax over keys (row = l16)
    float cmax = -1e30f;
#pragma unroll
    for (int jc = 0; jc < 7; ++jc)
#pragma unroll
      for (int st = 0; st < 2; ++st)
#pragma unroll
        for (int r = 0; r < 4; ++r) {
          int jg = jc * 32 + st * 16 + quad * 4 + r;
          float v = s[jc][st][r] * sc;
          v = (jg >= NTOK || jg == mg) ? -1e30f : v;
          s[jc][st][r] = v;
          cmax = fmaxf(cmax, v);
        }
    cmax = fmaxf(cmax, __shfl_xor(cmax, 16));
    cmax = fmaxf(cmax, __shfl_xor(cmax, 32));
    float psum = 0.f;
#pragma unroll
    for (int jc = 0; jc < 7; ++jc)
#pragma unroll
      for (int st = 0; st < 2; ++st)
#pragma unroll
        for (int r = 0; r < 4; ++r) {
          float e = __expf(s[jc][st][r] - cmax);
          psum += e;
          s[jc][st][r] = e;
        }
    psum += __shfl_xor(psum, 16);
    psum += __shfl_xor(psum, 32);
    const float inv = 1.0f / psum;

    // PV: O^T = V^T.P^T; P^T B-frags via shfl, V^T b128 from LDS
    f32x4 oacc[4];
#pragma unroll
    for (int dt = 0; dt < 4; ++dt) oacc[dt] = {0.f, 0.f, 0.f, 0.f};

#pragma unroll
    for (int jc = 0; jc < 7; ++jc) {
      uint32_t u0 = pack_bf2(s[jc][0][0], s[jc][0][1]);
      uint32_t v0 = pack_bf2(s[jc][0][2], s[jc][0][3]);
      uint32_t u1 = pack_bf2(s[jc][1][0], s[jc][1][1]);
      uint32_t v1 = pack_bf2(s[jc][1][2], s[jc][1][3]);
      uint32_t au0 = (uint32_t)__shfl((int)u0, srcA);
      uint32_t av0 = (uint32_t)__shfl((int)v0, srcA);
      uint32_t au1 = (uint32_t)__shfl((int)u1, srcA);
      uint32_t av1 = (uint32_t)__shfl((int)v1, srcA);
      uint32_t bu0 = (uint32_t)__shfl((int)u0, srcB);
      uint32_t bv0 = (uint32_t)__shfl((int)v0, srcB);
      uint32_t bu1 = (uint32_t)__shfl((int)u1, srcB);
      uint32_t bv1 = (uint32_t)__shfl((int)v1, srcB);
      union { uint32_t u[4]; bf16x8 v; } pb;
      pb.u[0] = stsel ? au1 : au0;
      pb.u[1] = stsel ? av1 : av0;
      pb.u[2] = stsel ? bu1 : bu0;
      pb.u[3] = stsel ? bv1 : bv0;
#pragma unroll
      for (int dt = 0; dt < 4; ++dt) {
        bf16x8 va = *(const bf16x8*)(Vt + (dt * 16 + l16) * VTS +
                                     jc * 32 + quad * 8);
        oacc[dt] = mfma16(va, pb.v, oacc[dt]);
      }
    }

    // O store via per-wave LDS bounce -> full 128B line stores
#pragma unroll
    for (int dt = 0; dt < 4; ++dt) {
      ushort4 pk;
      pk.x = f2bf(oacc[dt][0] * inv);
      pk.y = f2bf(oacc[dt][1] * inv);
      pk.z = f2bf(oacc[dt][2] * inv);
      pk.w = f2bf(oacc[dt][3] * inv);
      *(ushort4*)(ob + l16 * OBS + dt * 16 + quad * 4) = pk;
    }
    __asm__ __volatile__("s_waitcnt lgkmcnt(0)" ::: "memory");
#pragma unroll
    for (int rnd = 0; rnd < 4; ++rnd) {
      int q   = rnd * 4 + (lane >> 4);
      int o8  = lane & 15;
      uint2 d8 = *(const uint2*)(ob + q * OBS + o8 * 4);
      int qrow = mt * 16 + q;
      if (qrow < NTOK) {
        size_t obase = (size_t)(b * NTOK + qrow) * DIMC + h * HDIM;
        *(uint2*)(aout + obase + o8 * 4) = d8;
      }
    }
  }
}

// ---------------- launcher ----------------
extern "C" void kernel_launch(void* const* d_in, const int* in_sizes, int n_in,
                              void* d_out, int out_size, void* d_ws, size_t ws_size,
                              hipStream_t stream) {
  const float* x     = (const float*)d_in[0];
  const float* scale = (const float*)d_in[1];
  const float* wqkv  = (const float*)d_in[2];
  const float* wproj = (const float*)d_in[3];
  const float* bproj = (const float*)d_in[4];
  float* out = (float*)d_out;

  // ws layout (ushort), ~82.2 MB (R6-proven). attb aliases xb.
  unsigned short* xb   = (unsigned short*)d_ws;
  unsigned short* wqb  = xb  + (size_t)MTOK * DIMC;
  unsigned short* wpb  = wqb + (size_t)QKVO * DIMC;
  unsigned short* qkvb = wpb + (size_t)DIMC * DIMC;
  unsigned short* attb = xb;                          // alias

  cvt_all<<<CVNB, 256, 0, stream>>>(x, wqkv, wproj, xb, wqb, wpb);
  gemm_qkv<<<GM * (QKVO / 128), 256, 0, stream>>>(xb, wqb, qkvb);
  attn_fused<<<BH, 256, 0, stream>>>(qkvb, scale, attb);
  gemm_proj<<<GM64 * (DIMC / 128), 256, 0, stream>>>(attb, wpb, bproj, x, out);
}